// Round 16
// baseline (164.478 us; speedup 1.0000x reference)
//
#include <hip/hip_runtime.h>
#include <hip/hip_bf16.h>

#define NB 32
#define NJ 48
#define NI 48
#define NCTX 5
#define NE 128
#define NH 256
#define NVS 32000
#define NS 96
#define NR 3072   // 2*B*J rows

typedef __attribute__((ext_vector_type(8))) short bf16x8;
typedef __attribute__((ext_vector_type(4))) float f32x4;
typedef __attribute__((ext_vector_type(8))) int i32x8;

#if __has_builtin(__builtin_amdgcn_exp2f)
#define EXP2(x) __builtin_amdgcn_exp2f(x)
#else
#define EXP2(x) exp2f(x)
#endif

__device__ __forceinline__ unsigned short f2b(float f) {
  __hip_bfloat16 h = __float2bfloat16(f);
  return *reinterpret_cast<unsigned short*>(&h);
}
__device__ __forceinline__ float wave_sum(float v) {
  v += __shfl_xor(v, 1);
  v += __shfl_xor(v, 2);
  v += __shfl_xor(v, 4);
  v += __shfl_xor(v, 8);
  v += __shfl_xor(v, 16);
  v += __shfl_xor(v, 32);
  return v;
}
__device__ __forceinline__ void gload_lds16(const void* g, void* l) {
  __builtin_amdgcn_global_load_lds(
      (const __attribute__((address_space(1))) void*)g,
      (__attribute__((address_space(3))) void*)l, 16, 0, 0);
}

// Global fp8 layouts are 8B-slot permuted for conflict-free ds_read_b64 and
// aligned direct b64 global reads:
//   hb8 (A-style, 256B rows):  slot s (0..31) stored at s ^ (row & 15)
//   Wv8 (B-style, per 64B chunk): slot s (0..7) stored at s ^ ((row>>1) & 7)
// Wv8 values carry an extra log2(e) factor so MFMA output = logit*log2e;
// softmax then uses native 2^x (v_exp_f32) + precomputed ebv = exp(bv).

// ---- W_vocab -> Wv8 fp8 (x64*log2e), plus ebv[v]=exp(bv[v]) on by==0 ----
__global__ __launch_bounds__(256) void k_transpose(const float* __restrict__ Wv,
                                                   unsigned char* __restrict__ Wv8,
                                                   const float* __restrict__ bv,
                                                   float* __restrict__ ebv) {
  __shared__ float tile[64][65];
  int t = threadIdx.x;
  int v0 = blockIdx.x * 64, k0 = blockIdx.y * 64;
  if (blockIdx.y == 0 && t < 64) ebv[v0 + t] = __expf(bv[v0 + t]);
  {
    int kr = t >> 4, vq = t & 15;
#pragma unroll
    for (int it = 0; it < 4; ++it) {
      float4 v = *(const float4*)&Wv[(k0 + kr + 16 * it) * NVS + v0 + vq * 4];
      tile[kr + 16 * it][vq * 4 + 0] = v.x;
      tile[kr + 16 * it][vq * 4 + 1] = v.y;
      tile[kr + 16 * it][vq * 4 + 2] = v.z;
      tile[kr + 16 * it][vq * 4 + 3] = v.w;
    }
  }
  __syncthreads();
  {
    const float WS = 64.0f * 1.44269504088896f;   // x64 * log2(e)
    int vl = t >> 2, kq = t & 3;
    unsigned int q8[4];
#pragma unroll
    for (int d = 0; d < 4; ++d) {
      float f0 = tile[kq * 16 + d * 4 + 0][vl] * WS;
      float f1 = tile[kq * 16 + d * 4 + 1][vl] * WS;
      float f2 = tile[kq * 16 + d * 4 + 2][vl] * WS;
      float f3 = tile[kq * 16 + d * 4 + 3][vl] * WS;
      int w = __builtin_amdgcn_cvt_pk_fp8_f32(f0, f1, 0, false);
      w = __builtin_amdgcn_cvt_pk_fp8_f32(f2, f3, w, true);
      q8[d] = (unsigned int)w;
    }
    // B-layout permute: unit kq -> kq ^ ((r>>2)&3), halves swapped if (r>>1)&1
    int kqp = kq ^ ((vl >> 2) & 3);
    unsigned int q8s[4];
    if ((vl >> 1) & 1) {
      q8s[0] = q8[2]; q8s[1] = q8[3]; q8s[2] = q8[0]; q8s[3] = q8[1];
    } else {
      q8s[0] = q8[0]; q8s[1] = q8[1]; q8s[2] = q8[2]; q8s[3] = q8[3];
    }
    *(uint4*)&Wv8[(v0 + vl) * 256 + k0 + kqp * 16] = *(uint4*)q8s;
  }
}

// ---- generic transpose-convert: src [R][C] f32 -> dst [C][R] bf16 ----
__global__ __launch_bounds__(256) void k_t2b(const float* __restrict__ src,
                                             unsigned short* __restrict__ dst,
                                             int R, int C) {
  __shared__ float tile[64][65];
  int t = threadIdx.x;
  int r0 = blockIdx.x * 64, c0 = blockIdx.y * 64;
  {
    int rr = t >> 4, cq = t & 15;
#pragma unroll
    for (int it = 0; it < 4; ++it) {
      float4 v = *(const float4*)&src[(r0 + rr + 16 * it) * C + c0 + cq * 4];
      tile[rr + 16 * it][cq * 4 + 0] = v.x;
      tile[rr + 16 * it][cq * 4 + 1] = v.y;
      tile[rr + 16 * it][cq * 4 + 2] = v.z;
      tile[rr + 16 * it][cq * 4 + 3] = v.w;
    }
  }
  __syncthreads();
  {
    int cc = t >> 2, rq = t & 3;
    unsigned short pk[16];
#pragma unroll
    for (int q = 0; q < 16; ++q) pk[q] = f2b(tile[rq * 16 + q][cc]);
    *(uint4*)&dst[(c0 + cc) * R + r0 + rq * 16] = *(uint4*)&pk[0];
    *(uint4*)&dst[(c0 + cc) * R + r0 + rq * 16 + 8] = *(uint4*)&pk[8];
  }
}

// ---- GEMM1: xb[3072][128] bf16 = gather(emb) @ Wb ; MFMA, 32-row tiles ----
__global__ __launch_bounds__(256) void k_xb(const float* __restrict__ emb,
                                            const unsigned short* __restrict__ Wbt,
                                            const int* __restrict__ tc, const int* __restrict__ tcn,
                                            unsigned short* __restrict__ xb) {
  __shared__ unsigned short Ax[32 * 72];
  __shared__ unsigned short Bw[128 * 72];
  __shared__ unsigned short xout[32 * 136];
  int t = threadIdx.x;
  int r0 = blockIdx.x * 32;
  int wave = t >> 6, lane = t & 63;
  int wm = wave >> 1, wn = wave & 1;
  int lg = lane >> 4, lr = lane & 15;
  int arow = t >> 3, aseg = t & 7;
  int r = r0 + arow;
  int half = r / 1536, rem = r % 1536, bb = rem / 48, jj = rem % 48;
  const int* ids = half ? tcn : tc;
  int brow = t >> 1, bseg = t & 1;

  f32x4 acc[4];
#pragma unroll
  for (int n = 0; n < 4; ++n) acc[n] = (f32x4){0.f, 0.f, 0.f, 0.f};

  for (int step = 0; step < 10; ++step) {
    int k0 = step * 64;
    int p = step >> 1;
    int e0 = (step & 1) * 64;
    {
      int id = ids[bb * 240 + jj * 5 + p];
      const float4* er = (const float4*)&emb[id * 128 + e0 + aseg * 8];
      float4 v0 = er[0], v1 = er[1];
      unsigned short pk[8];
      pk[0] = f2b(v0.x); pk[1] = f2b(v0.y); pk[2] = f2b(v0.z); pk[3] = f2b(v0.w);
      pk[4] = f2b(v1.x); pk[5] = f2b(v1.y); pk[6] = f2b(v1.z); pk[7] = f2b(v1.w);
      *(uint4*)&Ax[arow * 72 + aseg * 8] = *(uint4*)&pk[0];
    }
    {
      const uint4* wp = (const uint4*)&Wbt[brow * 640 + k0 + bseg * 32];
      uint4* dp = (uint4*)&Bw[brow * 72 + bseg * 32];
      uint4 w0 = wp[0], w1 = wp[1], w2 = wp[2], w3 = wp[3];
      dp[0] = w0; dp[1] = w1; dp[2] = w2; dp[3] = w3;
    }
    __syncthreads();
#pragma unroll
    for (int kk = 0; kk < 2; ++kk) {
      bf16x8 a = *(const bf16x8*)&Ax[(wm * 16 + lr) * 72 + kk * 32 + lg * 8];
#pragma unroll
      for (int n = 0; n < 4; ++n) {
        bf16x8 b = *(const bf16x8*)&Bw[(wn * 64 + n * 16 + lr) * 72 + kk * 32 + lg * 8];
        acc[n] = __builtin_amdgcn_mfma_f32_16x16x32_bf16(a, b, acc[n], 0, 0, 0);
      }
    }
    __syncthreads();
  }
#pragma unroll
  for (int n = 0; n < 4; ++n)
#pragma unroll
    for (int g = 0; g < 4; ++g)
      xout[(wm * 16 + lg * 4 + g) * 136 + wn * 64 + n * 16 + lr] = f2b(acc[n][g]);
  __syncthreads();
  {
    int orow = t >> 3, os = t & 7;
    *(uint4*)&xb[(r0 + orow) * 128 + os * 16] = *(uint4*)&xout[orow * 136 + os * 16];
    *(uint4*)&xb[(r0 + orow) * 128 + os * 16 + 8] = *(uint4*)&xout[orow * 136 + os * 16 + 8];
  }
}

// ---- GEMM2: h = tanh(xb @ Wh + bh) -> fp8 hb8 [3072][256] (A-layout permuted) ----
__global__ __launch_bounds__(256) void k_h(const unsigned short* __restrict__ xb,
                                           const unsigned short* __restrict__ Wht,
                                           const float* __restrict__ bh,
                                           unsigned char* __restrict__ hb8) {
  __shared__ char smem[69632];
  unsigned short* Asm = (unsigned short*)smem;            // [128][136]
  unsigned short* Bsm = (unsigned short*)(smem + 34816);  // [128][136]
  unsigned char* o8 = (unsigned char*)smem;               // reuse: [128][144]
  int t = threadIdx.x;
  int r0 = blockIdx.x * 128, n0 = blockIdx.y * 128;
  int wave = t >> 6, lane = t & 63;
  int wm = wave >> 1, wn = wave & 1;
  int lg = lane >> 4, lr = lane & 15;
  {
    int row = t >> 1, seg = t & 1;
#pragma unroll
    for (int i = 0; i < 8; ++i) {
      *(uint4*)&Asm[row * 136 + seg * 64 + i * 8] = *(const uint4*)&xb[(r0 + row) * 128 + seg * 64 + i * 8];
      *(uint4*)&Bsm[row * 136 + seg * 64 + i * 8] = *(const uint4*)&Wht[(n0 + row) * 128 + seg * 64 + i * 8];
    }
  }
  __syncthreads();
  f32x4 acc[4][4];
#pragma unroll
  for (int m = 0; m < 4; ++m)
#pragma unroll
    for (int n = 0; n < 4; ++n) acc[m][n] = (f32x4){0.f, 0.f, 0.f, 0.f};
#pragma unroll
  for (int kk = 0; kk < 4; ++kk) {
    bf16x8 a[4], b[4];
#pragma unroll
    for (int m = 0; m < 4; ++m)
      a[m] = *(const bf16x8*)&Asm[(wm * 64 + m * 16 + lr) * 136 + kk * 32 + lg * 8];
#pragma unroll
    for (int n = 0; n < 4; ++n)
      b[n] = *(const bf16x8*)&Bsm[(wn * 64 + n * 16 + lr) * 136 + kk * 32 + lg * 8];
#pragma unroll
    for (int m = 0; m < 4; ++m)
#pragma unroll
      for (int n = 0; n < 4; ++n)
        acc[m][n] = __builtin_amdgcn_mfma_f32_16x16x32_bf16(a[m], b[n], acc[m][n], 0, 0, 0);
  }
  __syncthreads();
#pragma unroll
  for (int n = 0; n < 4; ++n) {
    int cl = wn * 64 + n * 16 + lr;
    float bvv = bh[n0 + cl];
#pragma unroll
    for (int m = 0; m < 4; ++m) {
#pragma unroll
      for (int g = 0; g < 4; ++g) {
        int rl = wm * 64 + m * 16 + lg * 4 + g;
        float hv = tanhf(acc[m][n][g] + bvv);
        int p8 = __builtin_amdgcn_cvt_pk_fp8_f32(hv * 256.0f, 0.0f, 0, false);
        o8[rl * 144 + cl] = (unsigned char)(p8 & 0xFF);
      }
    }
  }
  __syncthreads();
  // permuted store: dest unit p <- logical unit p ^ ((row>>1)&7), halves swapped if row&1
  {
    int row = t >> 1, seg = t & 1;
    int sig = (row >> 1) & 7;
    int swp = row & 1;
#pragma unroll
    for (int i = 0; i < 4; ++i) {
      int p_loc = seg * 4 + i;
      int w_loc = p_loc ^ sig;
      unsigned long long q[2];
      q[0] = *(const unsigned long long*)&o8[row * 144 + w_loc * 16 + swp * 8];
      q[1] = *(const unsigned long long*)&o8[row * 144 + w_loc * 16 + (swp ^ 1) * 8];
      *(uint4*)&hb8[(r0 + row) * 256 + n0 + p_loc * 16] = *(uint4*)q;
    }
  }
}

// ---- denominator GEMM via MX-scaled fp8 MFMA (16x16x128), ONE-BARRIER ----
// All 4 B chunks (64KB = full LDS) staged upfront (wave w stages chunk w);
// A fragments direct global->reg (permuted layout: slot = logical^lr);
// single __syncthreads, then pure free-running compute. No setprio.
__global__ __launch_bounds__(256) void k_denom(const unsigned char* __restrict__ hb8,
                                               const unsigned char* __restrict__ Wv8,
                                               const float* __restrict__ ebv,
                                               float* __restrict__ dpart) {
  __shared__ __align__(16) unsigned char smem[65536];   // chunk c @ c*16384
  int t = threadIdx.x;
  int bid = blockIdx.x;                 // 3000 = 8 * 375
  int xcd = bid & 7, pos = bid >> 3;
  int tl = xcd * 375 + pos;
  int vtp = tl / 24, rt = tl % 24;
  int r0 = rt * 128;
  int wave = t >> 6, lane = t & 63;
  int wm = wave >> 1, wn = wave & 1;
  int lg = lane >> 4, lr = lane & 15;

  // preload ebv for both vocab tiles
  float ebvv[2][4];
#pragma unroll
  for (int vt = 0; vt < 2; ++vt)
#pragma unroll
    for (int n = 0; n < 4; ++n)
      ebvv[vt][n] = ebv[(vtp * 2 + vt) * 128 + wn * 64 + n * 16 + lr];

  // stage ALL B: wave w owns chunk w (vt = w>>1, k = w&1); 16 insts x 1KB
  {
    int vt = wave >> 1, k = wave & 1;
    size_t vb = (size_t)((vtp * 2 + vt) * 128);
#pragma unroll
    for (int c = 0; c < 16; ++c) {
      int row = c * 8 + (lane >> 3);
      gload_lds16(&Wv8[(vb + row) * 256 + k * 128 + (lane & 7) * 16],
                  &smem[wave * 16384 + c * 1024]);
    }
  }
  // a_frag direct from global (L2-hot): row = r0 + wm*64 + m*16 + lr
  i32x8 a_frag[4][2];
#pragma unroll
  for (int m = 0; m < 4; ++m) {
    size_t rowb = (size_t)(r0 + wm * 64 + m * 16 + lr) * 256;
#pragma unroll
    for (int k = 0; k < 2; ++k) {
      union { long long l[4]; i32x8 v; } u;
#pragma unroll
      for (int j = 0; j < 4; ++j)
        u.l[j] = *(const long long*)&hb8[rowb + (((k * 16 + lg * 4 + j) ^ lr) << 3)];
      a_frag[m][k] = u.v;
    }
  }
  __syncthreads();   // single barrier: all stages + a_frag loads complete

  const unsigned int sa = 0x71717171u;   // E8M0 2^-14 per block (folds hx256 * wx64)
  const unsigned int sb = 0x7F7F7F7Fu;   // E8M0 1.0
  float rs_all[2][4][4];

#pragma unroll
  for (int vt = 0; vt < 2; ++vt) {
    f32x4 acc[4][4];
#pragma unroll
    for (int m = 0; m < 4; ++m)
#pragma unroll
      for (int n = 0; n < 4; ++n) acc[m][n] = (f32x4){0.f, 0.f, 0.f, 0.f};
#pragma unroll
    for (int k = 0; k < 2; ++k) {
      const unsigned char* bp = &smem[(vt * 2 + k) * 16384];
      i32x8 bfr[4];
#pragma unroll
      for (int n = 0; n < 4; ++n) {
        int rr = wn * 64 + n * 16 + lr;
        int sig = (rr >> 1) & 7;
        union { long long l[4]; i32x8 v; } u;
#pragma unroll
        for (int j = 0; j < 4; ++j) {
          int lb = lg * 32 + j * 8;        // logical byte in row's 128B chunk
          int h = lb >> 6;
          int sl = (lb >> 3) & 7;
          u.l[j] = *(const long long*)&bp[rr * 128 + h * 64 + ((sl ^ sig) << 3)];
        }
        bfr[n] = u.v;
      }
#pragma unroll
      for (int m = 0; m < 4; ++m)
#pragma unroll
        for (int n = 0; n < 4; ++n)
          acc[m][n] = __builtin_amdgcn_mfma_scale_f32_16x16x128_f8f6f4(
              a_frag[m][k], bfr[n], acc[m][n], 0, 0, 0, sa, 0, sb);
    }
    // epilogue: exp2 + rowsum for this vocab tile
    float rs[4][4];
#pragma unroll
    for (int m = 0; m < 4; ++m)
#pragma unroll
      for (int g = 0; g < 4; ++g) rs[m][g] = 0.f;
#pragma unroll
    for (int m = 0; m < 4; ++m) {
#pragma unroll
      for (int n = 0; n < 4; ++n) {
        float ev = ebvv[vt][n];
#pragma unroll
        for (int g = 0; g < 4; ++g) rs[m][g] += EXP2(acc[m][n][g]) * ev;
      }
    }
#pragma unroll
    for (int m = 0; m < 4; ++m)
#pragma unroll
      for (int g = 0; g < 4; ++g) {
        float v = rs[m][g];
        v += __shfl_xor(v, 1);
        v += __shfl_xor(v, 2);
        v += __shfl_xor(v, 4);
        v += __shfl_xor(v, 8);
        rs_all[vt][m][g] = v;
      }
  }

  if (lr == 0) {
#pragma unroll
    for (int vt = 0; vt < 2; ++vt) {
      int d = (vtp * 2 + vt) * 2 + wn;   // 500 slices
#pragma unroll
      for (int m = 0; m < 4; ++m)
#pragma unroll
        for (int g = 0; g < 4; ++g)
          dpart[(size_t)d * NR + r0 + wm * 64 + m * 16 + lg * 4 + g] = rs_all[vt][m][g];
    }
  }
}

// ---- reduce partial denominators (500 slices, 16 threads/row, 192 blocks) ----
__global__ __launch_bounds__(256) void k_reduce(const float* __restrict__ dpart,
                                                float* __restrict__ dsum) {
  int t = threadIdx.x;
  int r = blockIdx.x * 16 + (t >> 4);
  int q = t & 15;
  float s = 0.f;
  for (int vt = q; vt < 500; vt += 16) s += dpart[(size_t)vt * NR + r];
  s += __shfl_xor(s, 1);
  s += __shfl_xor(s, 2);
  s += __shfl_xor(s, 4);
  s += __shfl_xor(s, 8);
  if (q == 0) dsum[r] = s;
}

// ---- emission numerators via fp8 MFMA: one 64-thread block per (b,half) ----
__global__ __launch_bounds__(64) void k_emis(const unsigned char* __restrict__ hb8,
                                             const unsigned char* __restrict__ Wv8,
                                             const float* __restrict__ ebv,
                                             const float* __restrict__ dsum,
                                             const int* __restrict__ src,
                                             float* __restrict__ em) {
  __shared__ unsigned char A8[48 * 256];
  __shared__ unsigned char B8[48 * 256];
  __shared__ int s_src[48];
  int t = threadIdx.x;
  int bh = blockIdx.x;
  int b = bh & 31, half = bh >> 5;
  int row4 = t >> 4, seg = t & 15;
  int rbase = half * 1536 + b * 48;
  if (t < 48) s_src[t] = src[b * 48 + t];
#pragma unroll
  for (int c = 0; c < 12; ++c) {
    int row = c * 4 + row4;
    gload_lds16(&hb8[(rbase + row) * 256 + seg * 16], &A8[c * 1024]);
    int sv = src[b * 48 + row];
    gload_lds16(&Wv8[sv * 256 + seg * 16], &B8[c * 1024]);
  }
  __syncthreads();
  int lg = t >> 4, lr = t & 15;
  int svr[3];
  float ebr[3];
#pragma unroll
  for (int m = 0; m < 3; ++m) {
    svr[m] = s_src[m * 16 + lr];
    ebr[m] = ebv[svr[m]];
  }
  f32x4 acc[3][3];
#pragma unroll
  for (int m = 0; m < 3; ++m)
#pragma unroll
    for (int n = 0; n < 3; ++n) acc[m][n] = (f32x4){0.f, 0.f, 0.f, 0.f};
#pragma unroll
  for (int kk = 0; kk < 8; ++kk) {
    int sa = kk * 4 + lg;          // absolute 8B slot 0..31
    long long a[3], bb[3];
#pragma unroll
    for (int m = 0; m < 3; ++m) {
      int rr = m * 16 + lr;
      a[m] = *(const long long*)&A8[rr * 256 + ((sa ^ lr) << 3)];
      bb[m] = *(const long long*)&B8[rr * 256 + ((sa >> 3) << 6) +
                                     (((sa & 7) ^ ((svr[m] >> 1) & 7)) << 3)];
    }
#pragma unroll
    for (int m = 0; m < 3; ++m)
#pragma unroll
      for (int n = 0; n < 3; ++n)
        acc[m][n] = __builtin_amdgcn_mfma_f32_16x16x32_fp8_fp8(a[m], bb[n], acc[m][n], 0, 0, 0);
  }
  const float SC = 6.103515625e-05f;   // 2^-14; acc*SC = logit*log2e
#pragma unroll
  for (int n = 0; n < 3; ++n) {
    int i = n * 16 + lr;
    float ev = ebr[n];
#pragma unroll
    for (int m = 0; m < 3; ++m) {
#pragma unroll
      for (int g = 0; g < 4; ++g) {
        int j = m * 16 + lg * 4 + g;
        float val = EXP2(acc[m][n][g] * SC) * ev / dsum[rbase + j];
        em[b * 4608 + (half * 48 + j) * 48 + i] = val;
      }
    }
  }
}

// ---- fused HMM forward/backward: blocks 0..31 forward(batch), 32..63 backward(batch) ----
__global__ __launch_bounds__(192) void k_fb(const float* __restrict__ Atr, const float* __restrict__ pi,
                                            const float* __restrict__ em, float* __restrict__ alph,
                                            float* __restrict__ betas, float* __restrict__ out1) {
  __shared__ float A_st[96 * 97];
  __shared__ float em_lds[48 * 97];
  __shared__ __align__(16) float vec_lds[96];
  __shared__ float red[3];
  int t = threadIdx.x;
  int bid = blockIdx.x;
  int b = bid & 31;
  int role = bid >> 5;
  int col = t >> 1, half = t & 1;
  int base = b * 4608;

  for (int idx = t; idx < 96 * 96; idx += 192) {
    int s = idx / 96, tt = idx % 96;
    A_st[s * 97 + tt] = Atr[b * 9216 + idx];
  }
  for (int idx = t; idx < 96 * 48; idx += 192) {
    int s = idx / 48, i = idx % 48;
    em_lds[i * 97 + s] = em[base + idx];
  }
  __syncthreads();

  float Areg[48];
  if (role == 0) {
#pragma unroll
    for (int ss = 0; ss < 48; ++ss) Areg[ss] = A_st[(half * 48 + ss) * 97 + col];

    float llsum;
    {
      float v = pi[b * 96 + col] * em_lds[0 * 97 + col];
      float ws = half ? 0.f : v;
      ws = wave_sum(ws);
      if ((t & 63) == 0) red[t >> 6] = ws;
      __syncthreads();
      float c = red[0] + red[1] + red[2];
      float a = v / c;
      if (!half) {
        vec_lds[col] = a;
        alph[base + col] = a;
      }
      llsum = logf(c);
      __syncthreads();
    }
    for (int i = 1; i < 48; ++i) {
      float p = 0.f;
      const float4* ap = (const float4*)&vec_lds[half * 48];
#pragma unroll
      for (int q = 0; q < 12; ++q) {
        float4 av = ap[q];
        p += av.x * Areg[4 * q] + av.y * Areg[4 * q + 1] + av.z * Areg[4 * q + 2] + av.w * Areg[4 * q + 3];
      }
      p += __shfl_xor(p, 1);
      float an = p * em_lds[i * 97 + col];
      float ws = half ? 0.f : an;
      ws = wave_sum(ws);
      if ((t & 63) == 0) red[t >> 6] = ws;
      __syncthreads();
      float c = red[0] + red[1] + red[2];
      float a = an / c;
      if (!half) {
        vec_lds[col] = a;
        alph[base + i * 96 + col] = a;
      }
      llsum += logf(c);
      __syncthreads();
    }
    if (t == 0) out1[b] = -llsum;
  } else {
#pragma unroll
    for (int tt = 0; tt < 48; ++tt) Areg[tt] = A_st[col * 97 + half * 48 + tt];

    if (!half) {
      betas[base + 47 * 96 + col] = 1.0f;
      vec_lds[col] = em_lds[47 * 97 + col];
    }
    __syncthreads();
    for (int i = 46; i >= 0; --i) {
      float p = 0.f;
      const float4* ep = (const float4*)&vec_lds[half * 48];
#pragma unroll
      for (int q = 0; q < 12; ++q) {
        float4 ev = ep[q];
        p += ev.x * Areg[4 * q] + ev.y * Areg[4 * q + 1] + ev.z * Areg[4 * q + 2] + ev.w * Areg[4 * q + 3];
      }
      p += __shfl_xor(p, 1);
      float ws = half ? 0.f : p;
      ws = wave_sum(ws);
      if ((t & 63) == 0) red[t >> 6] = ws;
      __syncthreads();
      float c = red[0] + red[1] + red[2];
      float bt = p / c;
      if (!half) {
        betas[base + i * 96 + col] = bt;
        vec_lds[col] = em_lds[i * 97 + col] * bt;
      }
      __syncthreads();
    }
  }
}

// ---- gamma = alpha*beta, renormalized per (b,i); write transposed [b][s][i] ----
__global__ __launch_bounds__(128) void k_gamma(const float* __restrict__ alph,
                                               const float* __restrict__ betas,
                                               float* __restrict__ out0) {
  __shared__ float red[2];
  int b = blockIdx.x, i = blockIdx.y;
  int t = threadIdx.x;
  float g = 0.f;
  if (t < 96) g = alph[b * 4608 + i * 96 + t] * betas[b * 4608 + i * 96 + t];
  float ws = wave_sum(g);
  if ((t & 63) == 0) red[t >> 6] = ws;
  __syncthreads();
  float c = red[0] + red[1];
  if (t < 96) out0[b * 4608 + t * 48 + i] = g / c;
}

extern "C" void kernel_launch(void* const* d_in, const int* in_sizes, int n_in,
                              void* d_out, int out_size, void* d_ws, size_t ws_size,
                              hipStream_t stream) {
  const float* emb = (const float*)d_in[0];
  const float* Wb  = (const float*)d_in[1];
  const float* Wh  = (const float*)d_in[2];
  const float* bh  = (const float*)d_in[3];
  const float* Wv  = (const float*)d_in[4];
  const float* bv  = (const float*)d_in[5];
  const float* Atr = (const float*)d_in[6];
  const float* pi  = (const float*)d_in[7];
  const int* tc    = (const int*)d_in[8];
  const int* tcn   = (const int*)d_in[9];
  const int* src   = (const int*)d_in[10];

  float* out0 = (float*)d_out;
  float* out1 = out0 + NB * NS * NI;

  char* ws = (char*)d_ws;
  unsigned char* wv8 = (unsigned char*)(ws);                    //  8,192,000 B
  unsigned char* hb8 = (unsigned char*)(ws + 8192000);          //    786,432 B
  float* dpart       = (float*)(ws + 8978432);                  //  6,144,000 B (500 slices)
  float* betas       = (float*)(ws + 8978432);                  //  reuse: dpart dead after k_reduce
  float* dsum        = (float*)(ws + 15122432);                 //     12,288 B
  float* em          = (float*)(ws + 15134720);                 //    589,824 B
  float* alph        = (float*)(ws + 15724544);                 //    589,824 B
  unsigned short* wbt = (unsigned short*)(ws + 16314368);       //    163,840 B
  unsigned short* wht = (unsigned short*)(ws + 16478208);       //     65,536 B
  unsigned short* xb  = (unsigned short*)(ws + 16543744);       //    786,432 B
  float* ebv          = (float*)(ws + 17330176);                //    128,000 B

  k_transpose<<<dim3(500, 4), 256, 0, stream>>>(Wv, wv8, bv, ebv);
  k_t2b<<<dim3(10, 2), 256, 0, stream>>>(Wb, wbt, 640, 128);
  k_t2b<<<dim3(2, 4), 256, 0, stream>>>(Wh, wht, 128, 256);
  k_xb<<<96, 256, 0, stream>>>(emb, wbt, tc, tcn, xb);
  k_h<<<dim3(24, 2), 256, 0, stream>>>(xb, wht, bh, hb8);
  k_denom<<<3000, 256, 0, stream>>>(hb8, wv8, ebv, dpart);
  k_reduce<<<192, 256, 0, stream>>>(dpart, dsum);
  k_emis<<<64, 64, 0, stream>>>(hb8, wv8, ebv, dsum, src, em);
  k_fb<<<64, 192, 0, stream>>>(Atr, pi, em, alph, betas, out1);
  k_gamma<<<dim3(32, 48), 128, 0, stream>>>(alph, betas, out0);
}

// Round 17
// 145.742 us; speedup vs baseline: 1.1286x; 1.1286x over previous
//
#include <hip/hip_runtime.h>
#include <hip/hip_bf16.h>

#define NB 32
#define NJ 48
#define NI 48
#define NCTX 5
#define NE 128
#define NH 256
#define NVS 32000
#define NS 96
#define NR 3072   // 2*B*J rows

typedef __attribute__((ext_vector_type(8))) short bf16x8;
typedef __attribute__((ext_vector_type(4))) float f32x4;
typedef __attribute__((ext_vector_type(8))) int i32x8;

#if __has_builtin(__builtin_amdgcn_exp2f)
#define EXP2(x) __builtin_amdgcn_exp2f(x)
#else
#define EXP2(x) exp2f(x)
#endif

__device__ __forceinline__ unsigned short f2b(float f) {
  __hip_bfloat16 h = __float2bfloat16(f);
  return *reinterpret_cast<unsigned short*>(&h);
}
__device__ __forceinline__ float wave_sum(float v) {
  v += __shfl_xor(v, 1);
  v += __shfl_xor(v, 2);
  v += __shfl_xor(v, 4);
  v += __shfl_xor(v, 8);
  v += __shfl_xor(v, 16);
  v += __shfl_xor(v, 32);
  return v;
}
__device__ __forceinline__ void gload_lds16(const void* g, void* l) {
  __builtin_amdgcn_global_load_lds(
      (const __attribute__((address_space(1))) void*)g,
      (__attribute__((address_space(3))) void*)l, 16, 0, 0);
}

// Global fp8 layouts are 8B-slot permuted for conflict-free ds_read_b64:
//   hb8 (A-style, 256B rows):  slot s (0..31) stored at s ^ (row & 15)
//   Wv8 (B-style, per 64B chunk): slot s (0..7) stored at s ^ ((row>>1) & 7)
// Wv8 values carry an extra log2(e) factor so MFMA output = logit*log2e;
// softmax then uses native 2^x (v_exp_f32) + precomputed ebv = exp(bv).

// ---- W_vocab -> Wv8 fp8 (x64*log2e), plus ebv[v]=exp(bv[v]) on by==0 ----
__global__ __launch_bounds__(256) void k_transpose(const float* __restrict__ Wv,
                                                   unsigned char* __restrict__ Wv8,
                                                   const float* __restrict__ bv,
                                                   float* __restrict__ ebv) {
  __shared__ float tile[64][65];
  int t = threadIdx.x;
  int v0 = blockIdx.x * 64, k0 = blockIdx.y * 64;
  if (blockIdx.y == 0 && t < 64) ebv[v0 + t] = __expf(bv[v0 + t]);
  {
    int kr = t >> 4, vq = t & 15;
#pragma unroll
    for (int it = 0; it < 4; ++it) {
      float4 v = *(const float4*)&Wv[(k0 + kr + 16 * it) * NVS + v0 + vq * 4];
      tile[kr + 16 * it][vq * 4 + 0] = v.x;
      tile[kr + 16 * it][vq * 4 + 1] = v.y;
      tile[kr + 16 * it][vq * 4 + 2] = v.z;
      tile[kr + 16 * it][vq * 4 + 3] = v.w;
    }
  }
  __syncthreads();
  {
    const float WS = 64.0f * 1.44269504088896f;   // x64 * log2(e)
    int vl = t >> 2, kq = t & 3;
    unsigned int q8[4];
#pragma unroll
    for (int d = 0; d < 4; ++d) {
      float f0 = tile[kq * 16 + d * 4 + 0][vl] * WS;
      float f1 = tile[kq * 16 + d * 4 + 1][vl] * WS;
      float f2 = tile[kq * 16 + d * 4 + 2][vl] * WS;
      float f3 = tile[kq * 16 + d * 4 + 3][vl] * WS;
      int w = __builtin_amdgcn_cvt_pk_fp8_f32(f0, f1, 0, false);
      w = __builtin_amdgcn_cvt_pk_fp8_f32(f2, f3, w, true);
      q8[d] = (unsigned int)w;
    }
    // B-layout permute: unit kq -> kq ^ ((r>>2)&3), halves swapped if (r>>1)&1
    int kqp = kq ^ ((vl >> 2) & 3);
    unsigned int q8s[4];
    if ((vl >> 1) & 1) {
      q8s[0] = q8[2]; q8s[1] = q8[3]; q8s[2] = q8[0]; q8s[3] = q8[1];
    } else {
      q8s[0] = q8[0]; q8s[1] = q8[1]; q8s[2] = q8[2]; q8s[3] = q8[3];
    }
    *(uint4*)&Wv8[(v0 + vl) * 256 + k0 + kqp * 16] = *(uint4*)q8s;
  }
}

// ---- generic transpose-convert: src [R][C] f32 -> dst [C][R] bf16 ----
__global__ __launch_bounds__(256) void k_t2b(const float* __restrict__ src,
                                             unsigned short* __restrict__ dst,
                                             int R, int C) {
  __shared__ float tile[64][65];
  int t = threadIdx.x;
  int r0 = blockIdx.x * 64, c0 = blockIdx.y * 64;
  {
    int rr = t >> 4, cq = t & 15;
#pragma unroll
    for (int it = 0; it < 4; ++it) {
      float4 v = *(const float4*)&src[(r0 + rr + 16 * it) * C + c0 + cq * 4];
      tile[rr + 16 * it][cq * 4 + 0] = v.x;
      tile[rr + 16 * it][cq * 4 + 1] = v.y;
      tile[rr + 16 * it][cq * 4 + 2] = v.z;
      tile[rr + 16 * it][cq * 4 + 3] = v.w;
    }
  }
  __syncthreads();
  {
    int cc = t >> 2, rq = t & 3;
    unsigned short pk[16];
#pragma unroll
    for (int q = 0; q < 16; ++q) pk[q] = f2b(tile[rq * 16 + q][cc]);
    *(uint4*)&dst[(c0 + cc) * R + r0 + rq * 16] = *(uint4*)&pk[0];
    *(uint4*)&dst[(c0 + cc) * R + r0 + rq * 16 + 8] = *(uint4*)&pk[8];
  }
}

// ---- GEMM1: xb[3072][128] bf16 = gather(emb) @ Wb ; MFMA, 32-row tiles ----
__global__ __launch_bounds__(256) void k_xb(const float* __restrict__ emb,
                                            const unsigned short* __restrict__ Wbt,
                                            const int* __restrict__ tc, const int* __restrict__ tcn,
                                            unsigned short* __restrict__ xb) {
  __shared__ unsigned short Ax[32 * 72];
  __shared__ unsigned short Bw[128 * 72];
  __shared__ unsigned short xout[32 * 136];
  int t = threadIdx.x;
  int r0 = blockIdx.x * 32;
  int wave = t >> 6, lane = t & 63;
  int wm = wave >> 1, wn = wave & 1;
  int lg = lane >> 4, lr = lane & 15;
  int arow = t >> 3, aseg = t & 7;
  int r = r0 + arow;
  int half = r / 1536, rem = r % 1536, bb = rem / 48, jj = rem % 48;
  const int* ids = half ? tcn : tc;
  int brow = t >> 1, bseg = t & 1;

  f32x4 acc[4];
#pragma unroll
  for (int n = 0; n < 4; ++n) acc[n] = (f32x4){0.f, 0.f, 0.f, 0.f};

  for (int step = 0; step < 10; ++step) {
    int k0 = step * 64;
    int p = step >> 1;
    int e0 = (step & 1) * 64;
    {
      int id = ids[bb * 240 + jj * 5 + p];
      const float4* er = (const float4*)&emb[id * 128 + e0 + aseg * 8];
      float4 v0 = er[0], v1 = er[1];
      unsigned short pk[8];
      pk[0] = f2b(v0.x); pk[1] = f2b(v0.y); pk[2] = f2b(v0.z); pk[3] = f2b(v0.w);
      pk[4] = f2b(v1.x); pk[5] = f2b(v1.y); pk[6] = f2b(v1.z); pk[7] = f2b(v1.w);
      *(uint4*)&Ax[arow * 72 + aseg * 8] = *(uint4*)&pk[0];
    }
    {
      const uint4* wp = (const uint4*)&Wbt[brow * 640 + k0 + bseg * 32];
      uint4* dp = (uint4*)&Bw[brow * 72 + bseg * 32];
      uint4 w0 = wp[0], w1 = wp[1], w2 = wp[2], w3 = wp[3];
      dp[0] = w0; dp[1] = w1; dp[2] = w2; dp[3] = w3;
    }
    __syncthreads();
#pragma unroll
    for (int kk = 0; kk < 2; ++kk) {
      bf16x8 a = *(const bf16x8*)&Ax[(wm * 16 + lr) * 72 + kk * 32 + lg * 8];
#pragma unroll
      for (int n = 0; n < 4; ++n) {
        bf16x8 b = *(const bf16x8*)&Bw[(wn * 64 + n * 16 + lr) * 72 + kk * 32 + lg * 8];
        acc[n] = __builtin_amdgcn_mfma_f32_16x16x32_bf16(a, b, acc[n], 0, 0, 0);
      }
    }
    __syncthreads();
  }
#pragma unroll
  for (int n = 0; n < 4; ++n)
#pragma unroll
    for (int g = 0; g < 4; ++g)
      xout[(wm * 16 + lg * 4 + g) * 136 + wn * 64 + n * 16 + lr] = f2b(acc[n][g]);
  __syncthreads();
  {
    int orow = t >> 3, os = t & 7;
    *(uint4*)&xb[(r0 + orow) * 128 + os * 16] = *(uint4*)&xout[orow * 136 + os * 16];
    *(uint4*)&xb[(r0 + orow) * 128 + os * 16 + 8] = *(uint4*)&xout[orow * 136 + os * 16 + 8];
  }
}

// ---- GEMM2: h = tanh(xb @ Wh + bh) -> fp8 hb8 [3072][256] (A-layout permuted) ----
__global__ __launch_bounds__(256) void k_h(const unsigned short* __restrict__ xb,
                                           const unsigned short* __restrict__ Wht,
                                           const float* __restrict__ bh,
                                           unsigned char* __restrict__ hb8) {
  __shared__ char smem[69632];
  unsigned short* Asm = (unsigned short*)smem;            // [128][136]
  unsigned short* Bsm = (unsigned short*)(smem + 34816);  // [128][136]
  unsigned char* o8 = (unsigned char*)smem;               // reuse: [128][144]
  int t = threadIdx.x;
  int r0 = blockIdx.x * 128, n0 = blockIdx.y * 128;
  int wave = t >> 6, lane = t & 63;
  int wm = wave >> 1, wn = wave & 1;
  int lg = lane >> 4, lr = lane & 15;
  {
    int row = t >> 1, seg = t & 1;
#pragma unroll
    for (int i = 0; i < 8; ++i) {
      *(uint4*)&Asm[row * 136 + seg * 64 + i * 8] = *(const uint4*)&xb[(r0 + row) * 128 + seg * 64 + i * 8];
      *(uint4*)&Bsm[row * 136 + seg * 64 + i * 8] = *(const uint4*)&Wht[(n0 + row) * 128 + seg * 64 + i * 8];
    }
  }
  __syncthreads();
  f32x4 acc[4][4];
#pragma unroll
  for (int m = 0; m < 4; ++m)
#pragma unroll
    for (int n = 0; n < 4; ++n) acc[m][n] = (f32x4){0.f, 0.f, 0.f, 0.f};
#pragma unroll
  for (int kk = 0; kk < 4; ++kk) {
    bf16x8 a[4], b[4];
#pragma unroll
    for (int m = 0; m < 4; ++m)
      a[m] = *(const bf16x8*)&Asm[(wm * 64 + m * 16 + lr) * 136 + kk * 32 + lg * 8];
#pragma unroll
    for (int n = 0; n < 4; ++n)
      b[n] = *(const bf16x8*)&Bsm[(wn * 64 + n * 16 + lr) * 136 + kk * 32 + lg * 8];
#pragma unroll
    for (int m = 0; m < 4; ++m)
#pragma unroll
      for (int n = 0; n < 4; ++n)
        acc[m][n] = __builtin_amdgcn_mfma_f32_16x16x32_bf16(a[m], b[n], acc[m][n], 0, 0, 0);
  }
  __syncthreads();
#pragma unroll
  for (int n = 0; n < 4; ++n) {
    int cl = wn * 64 + n * 16 + lr;
    float bvv = bh[n0 + cl];
#pragma unroll
    for (int m = 0; m < 4; ++m) {
#pragma unroll
      for (int g = 0; g < 4; ++g) {
        int rl = wm * 64 + m * 16 + lg * 4 + g;
        float hv = tanhf(acc[m][n][g] + bvv);
        int p8 = __builtin_amdgcn_cvt_pk_fp8_f32(hv * 256.0f, 0.0f, 0, false);
        o8[rl * 144 + cl] = (unsigned char)(p8 & 0xFF);
      }
    }
  }
  __syncthreads();
  // permuted store: dest unit p <- logical unit p ^ ((row>>1)&7), halves swapped if row&1
  {
    int row = t >> 1, seg = t & 1;
    int sig = (row >> 1) & 7;
    int swp = row & 1;
#pragma unroll
    for (int i = 0; i < 4; ++i) {
      int p_loc = seg * 4 + i;
      int w_loc = p_loc ^ sig;
      unsigned long long q[2];
      q[0] = *(const unsigned long long*)&o8[row * 144 + w_loc * 16 + swp * 8];
      q[1] = *(const unsigned long long*)&o8[row * 144 + w_loc * 16 + (swp ^ 1) * 8];
      *(uint4*)&hb8[(r0 + row) * 256 + n0 + p_loc * 16] = *(uint4*)q;
    }
  }
}

// ---- denominator GEMM via MX-scaled fp8 MFMA (16x16x128) — pinned best ----
__global__ __launch_bounds__(256) void k_denom(const unsigned char* __restrict__ hb8,
                                               const unsigned char* __restrict__ Wv8,
                                               const float* __restrict__ ebv,
                                               float* __restrict__ dpart) {
  __shared__ __align__(16) unsigned char smem[32768];   // buf0 @0, buf1 @16384
  int t = threadIdx.x;
  int bid = blockIdx.x;                 // 3000 = 8 * 375
  int xcd = bid & 7, pos = bid >> 3;
  int tl = xcd * 375 + pos;
  int vtp = tl / 24, rt = tl % 24;
  int r0 = rt * 128;
  int wave = t >> 6, lane = t & 63;
  int wm = wave >> 1, wn = wave & 1;
  int lg = lane >> 4, lr = lane & 15;

  // preload ebv for both vocab tiles
  float ebvv[2][4];
#pragma unroll
  for (int vt = 0; vt < 2; ++vt)
#pragma unroll
    for (int n = 0; n < 4; ++n)
      ebvv[vt][n] = ebv[(vtp * 2 + vt) * 128 + wn * 64 + n * 16 + lr];

  // ---- stage A (32KB = whole smem) once, fill a_frag, then smem -> B bufs ----
#pragma unroll
  for (int c = 0; c < 8; ++c) {
    int inst = wave * 8 + c;             // 0..31, 1KB: rows inst*4 + (lane>>4)
    gload_lds16(&hb8[(size_t)(r0 + inst * 4 + (lane >> 4)) * 256 + (lane & 15) * 16],
                &smem[inst * 1024]);
  }
  __syncthreads();
  // a_frag[m][k]: 32 contiguous logical bytes at K = k*128 + lg*32 of row wm*64+m*16+lr
  i32x8 a_frag[4][2];
#pragma unroll
  for (int m = 0; m < 4; ++m) {
    int rowb = (wm * 64 + m * 16 + lr) * 256;
#pragma unroll
    for (int k = 0; k < 2; ++k) {
      union { long long l[4]; i32x8 v; } u;
#pragma unroll
      for (int j = 0; j < 4; ++j)
        u.l[j] = *(const long long*)&smem[rowb + (((k * 16 + lg * 4 + j) ^ lr) << 3)];
      a_frag[m][k] = u.v;
    }
  }
  __syncthreads();   // all A reads done -> smem reusable as B buffers

  // stage B step0 (vt0,k0): 16KB, 4 insts/wave, verbatim lane order
#pragma unroll
  for (int c = 0; c < 4; ++c) {
    int inst = wave * 4 + c;             // rows inst*8 + (lane>>3), 16B unit lane&7
    gload_lds16(&Wv8[(size_t)(vtp * 256 + inst * 8 + (lane >> 3)) * 256 + (lane & 7) * 16],
                &smem[inst * 1024]);
  }
  __syncthreads();

  const unsigned int sa = 0x71717171u;   // E8M0 2^-14 per block (folds hx256 * wx64)
  const unsigned int sb = 0x7F7F7F7Fu;   // E8M0 1.0
  f32x4 acc[4][4];
#pragma unroll
  for (int m = 0; m < 4; ++m)
#pragma unroll
    for (int n = 0; n < 4; ++n) acc[m][n] = (f32x4){0.f, 0.f, 0.f, 0.f};
  float rs_all[2][4][4];

#pragma unroll
  for (int s = 0; s < 4; ++s) {          // vt = s>>1, k = s&1
    if (s < 3) {
      int ns = s + 1;
      int nvt = ns >> 1, nk = ns & 1;
#pragma unroll
      for (int c = 0; c < 4; ++c) {
        int inst = wave * 4 + c;
        gload_lds16(&Wv8[(size_t)((vtp * 2 + nvt) * 128 + inst * 8 + (lane >> 3)) * 256 +
                         nk * 128 + (lane & 7) * 16],
                    &smem[((ns & 1) << 14) + inst * 1024]);
      }
    }
    const unsigned char* bp = &smem[(s & 1) << 14];
    i32x8 bfr[4];
#pragma unroll
    for (int n = 0; n < 4; ++n) {
      int rr = wn * 64 + n * 16 + lr;
      int sig = (rr >> 1) & 7;
      union { long long l[4]; i32x8 v; } u;
#pragma unroll
      for (int j = 0; j < 4; ++j) {
        int lb = lg * 32 + j * 8;        // logical byte in row's 128B chunk
        int h = lb >> 6;
        int sl = (lb >> 3) & 7;
        u.l[j] = *(const long long*)&bp[rr * 128 + h * 64 + ((sl ^ sig) << 3)];
      }
      bfr[n] = u.v;
    }
    int k = s & 1;
    __builtin_amdgcn_s_setprio(1);
#pragma unroll
    for (int m = 0; m < 4; ++m)
#pragma unroll
      for (int n = 0; n < 4; ++n)
        acc[m][n] = __builtin_amdgcn_mfma_scale_f32_16x16x128_f8f6f4(
            a_frag[m][k], bfr[n], acc[m][n], 0, 0, 0, sa, 0, sb);
    __builtin_amdgcn_s_setprio(0);
    if (k == 1) {
      int vt = s >> 1;
      float rs[4][4];
#pragma unroll
      for (int m = 0; m < 4; ++m)
#pragma unroll
        for (int g = 0; g < 4; ++g) rs[m][g] = 0.f;
#pragma unroll
      for (int m = 0; m < 4; ++m) {
#pragma unroll
        for (int n = 0; n < 4; ++n) {
          float ev = ebvv[vt][n];
#pragma unroll
          for (int g = 0; g < 4; ++g) rs[m][g] += EXP2(acc[m][n][g]) * ev;
          acc[m][n] = (f32x4){0.f, 0.f, 0.f, 0.f};
        }
      }
#pragma unroll
      for (int m = 0; m < 4; ++m)
#pragma unroll
        for (int g = 0; g < 4; ++g) {
          float v = rs[m][g];
          v += __shfl_xor(v, 1);
          v += __shfl_xor(v, 2);
          v += __shfl_xor(v, 4);
          v += __shfl_xor(v, 8);
          rs_all[vt][m][g] = v;
        }
    }
    __syncthreads();   // step-end: stage drained, buffer WAR guarded
  }

  if (lr == 0) {
#pragma unroll
    for (int vt = 0; vt < 2; ++vt) {
      int d = (vtp * 2 + vt) * 2 + wn;   // 500 slices
#pragma unroll
      for (int m = 0; m < 4; ++m)
#pragma unroll
        for (int g = 0; g < 4; ++g)
          dpart[(size_t)d * NR + r0 + wm * 64 + m * 16 + lg * 4 + g] = rs_all[vt][m][g];
    }
  }
}

// ---- reduce partial denominators (500 slices, 16 threads/row, 192 blocks) ----
__global__ __launch_bounds__(256) void k_reduce(const float* __restrict__ dpart,
                                                float* __restrict__ dsum) {
  int t = threadIdx.x;
  int r = blockIdx.x * 16 + (t >> 4);
  int q = t & 15;
  float s = 0.f;
  for (int vt = q; vt < 500; vt += 16) s += dpart[(size_t)vt * NR + r];
  s += __shfl_xor(s, 1);
  s += __shfl_xor(s, 2);
  s += __shfl_xor(s, 4);
  s += __shfl_xor(s, 8);
  if (q == 0) dsum[r] = s;
}

// ---- emission numerators via fp8 MFMA: one 64-thread block per (b,half) ----
__global__ __launch_bounds__(64) void k_emis(const unsigned char* __restrict__ hb8,
                                             const unsigned char* __restrict__ Wv8,
                                             const float* __restrict__ ebv,
                                             const float* __restrict__ dsum,
                                             const int* __restrict__ src,
                                             float* __restrict__ em) {
  __shared__ unsigned char A8[48 * 256];
  __shared__ unsigned char B8[48 * 256];
  __shared__ int s_src[48];
  int t = threadIdx.x;
  int bh = blockIdx.x;
  int b = bh & 31, half = bh >> 5;
  int row4 = t >> 4, seg = t & 15;
  int rbase = half * 1536 + b * 48;
  if (t < 48) s_src[t] = src[b * 48 + t];
#pragma unroll
  for (int c = 0; c < 12; ++c) {
    int row = c * 4 + row4;
    gload_lds16(&hb8[(rbase + row) * 256 + seg * 16], &A8[c * 1024]);
    int sv = src[b * 48 + row];
    gload_lds16(&Wv8[sv * 256 + seg * 16], &B8[c * 1024]);
  }
  __syncthreads();
  int lg = t >> 4, lr = t & 15;
  int svr[3];
  float ebr[3];
#pragma unroll
  for (int m = 0; m < 3; ++m) {
    svr[m] = s_src[m * 16 + lr];
    ebr[m] = ebv[svr[m]];
  }
  f32x4 acc[3][3];
#pragma unroll
  for (int m = 0; m < 3; ++m)
#pragma unroll
    for (int n = 0; n < 3; ++n) acc[m][n] = (f32x4){0.f, 0.f, 0.f, 0.f};
#pragma unroll
  for (int kk = 0; kk < 8; ++kk) {
    int sa = kk * 4 + lg;          // absolute 8B slot 0..31
    long long a[3], bb[3];
#pragma unroll
    for (int m = 0; m < 3; ++m) {
      int rr = m * 16 + lr;
      a[m] = *(const long long*)&A8[rr * 256 + ((sa ^ lr) << 3)];
      bb[m] = *(const long long*)&B8[rr * 256 + ((sa >> 3) << 6) +
                                     (((sa & 7) ^ ((svr[m] >> 1) & 7)) << 3)];
    }
#pragma unroll
    for (int m = 0; m < 3; ++m)
#pragma unroll
      for (int n = 0; n < 3; ++n)
        acc[m][n] = __builtin_amdgcn_mfma_f32_16x16x32_fp8_fp8(a[m], bb[n], acc[m][n], 0, 0, 0);
  }
  const float SC = 6.103515625e-05f;   // 2^-14; acc*SC = logit*log2e
#pragma unroll
  for (int n = 0; n < 3; ++n) {
    int i = n * 16 + lr;
    float ev = ebr[n];
#pragma unroll
    for (int m = 0; m < 3; ++m) {
#pragma unroll
      for (int g = 0; g < 4; ++g) {
        int j = m * 16 + lg * 4 + g;
        float val = EXP2(acc[m][n][g] * SC) * ev / dsum[rbase + j];
        em[b * 4608 + (half * 48 + j) * 48 + i] = val;
      }
    }
  }
}

// ---- fused HMM forward/backward: blocks 0..31 forward(batch), 32..63 backward(batch) ----
__global__ __launch_bounds__(192) void k_fb(const float* __restrict__ Atr, const float* __restrict__ pi,
                                            const float* __restrict__ em, float* __restrict__ alph,
                                            float* __restrict__ betas, float* __restrict__ out1) {
  __shared__ float A_st[96 * 97];
  __shared__ float em_lds[48 * 97];
  __shared__ __align__(16) float vec_lds[96];
  __shared__ float red[3];
  int t = threadIdx.x;
  int bid = blockIdx.x;
  int b = bid & 31;
  int role = bid >> 5;
  int col = t >> 1, half = t & 1;
  int base = b * 4608;

  for (int idx = t; idx < 96 * 96; idx += 192) {
    int s = idx / 96, tt = idx % 96;
    A_st[s * 97 + tt] = Atr[b * 9216 + idx];
  }
  for (int idx = t; idx < 96 * 48; idx += 192) {
    int s = idx / 48, i = idx % 48;
    em_lds[i * 97 + s] = em[base + idx];
  }
  __syncthreads();

  float Areg[48];
  if (role == 0) {
#pragma unroll
    for (int ss = 0; ss < 48; ++ss) Areg[ss] = A_st[(half * 48 + ss) * 97 + col];

    float llsum;
    {
      float v = pi[b * 96 + col] * em_lds[0 * 97 + col];
      float ws = half ? 0.f : v;
      ws = wave_sum(ws);
      if ((t & 63) == 0) red[t >> 6] = ws;
      __syncthreads();
      float c = red[0] + red[1] + red[2];
      float a = v / c;
      if (!half) {
        vec_lds[col] = a;
        alph[base + col] = a;
      }
      llsum = logf(c);
      __syncthreads();
    }
    for (int i = 1; i < 48; ++i) {
      float p = 0.f;
      const float4* ap = (const float4*)&vec_lds[half * 48];
#pragma unroll
      for (int q = 0; q < 12; ++q) {
        float4 av = ap[q];
        p += av.x * Areg[4 * q] + av.y * Areg[4 * q + 1] + av.z * Areg[4 * q + 2] + av.w * Areg[4 * q + 3];
      }
      p += __shfl_xor(p, 1);
      float an = p * em_lds[i * 97 + col];
      float ws = half ? 0.f : an;
      ws = wave_sum(ws);
      if ((t & 63) == 0) red[t >> 6] = ws;
      __syncthreads();
      float c = red[0] + red[1] + red[2];
      float a = an / c;
      if (!half) {
        vec_lds[col] = a;
        alph[base + i * 96 + col] = a;
      }
      llsum += logf(c);
      __syncthreads();
    }
    if (t == 0) out1[b] = -llsum;
  } else {
#pragma unroll
    for (int tt = 0; tt < 48; ++tt) Areg[tt] = A_st[col * 97 + half * 48 + tt];

    if (!half) {
      betas[base + 47 * 96 + col] = 1.0f;
      vec_lds[col] = em_lds[47 * 97 + col];
    }
    __syncthreads();
    for (int i = 46; i >= 0; --i) {
      float p = 0.f;
      const float4* ep = (const float4*)&vec_lds[half * 48];
#pragma unroll
      for (int q = 0; q < 12; ++q) {
        float4 ev = ep[q];
        p += ev.x * Areg[4 * q] + ev.y * Areg[4 * q + 1] + ev.z * Areg[4 * q + 2] + ev.w * Areg[4 * q + 3];
      }
      p += __shfl_xor(p, 1);
      float ws = half ? 0.f : p;
      ws = wave_sum(ws);
      if ((t & 63) == 0) red[t >> 6] = ws;
      __syncthreads();
      float c = red[0] + red[1] + red[2];
      float bt = p / c;
      if (!half) {
        betas[base + i * 96 + col] = bt;
        vec_lds[col] = em_lds[i * 97 + col] * bt;
      }
      __syncthreads();
    }
  }
}

// ---- gamma = alpha*beta, renormalized per (b,i); write transposed [b][s][i] ----
__global__ __launch_bounds__(128) void k_gamma(const float* __restrict__ alph,
                                               const float* __restrict__ betas,
                                               float* __restrict__ out0) {
  __shared__ float red[2];
  int b = blockIdx.x, i = blockIdx.y;
  int t = threadIdx.x;
  float g = 0.f;
  if (t < 96) g = alph[b * 4608 + i * 96 + t] * betas[b * 4608 + i * 96 + t];
  float ws = wave_sum(g);
  if ((t & 63) == 0) red[t >> 6] = ws;
  __syncthreads();
  float c = red[0] + red[1];
  if (t < 96) out0[b * 4608 + t * 48 + i] = g / c;
}

extern "C" void kernel_launch(void* const* d_in, const int* in_sizes, int n_in,
                              void* d_out, int out_size, void* d_ws, size_t ws_size,
                              hipStream_t stream) {
  const float* emb = (const float*)d_in[0];
  const float* Wb  = (const float*)d_in[1];
  const float* Wh  = (const float*)d_in[2];
  const float* bh  = (const float*)d_in[3];
  const float* Wv  = (const float*)d_in[4];
  const float* bv  = (const float*)d_in[5];
  const float* Atr = (const float*)d_in[6];
  const float* pi  = (const float*)d_in[7];
  const int* tc    = (const int*)d_in[8];
  const int* tcn   = (const int*)d_in[9];
  const int* src   = (const int*)d_in[10];

  float* out0 = (float*)d_out;
  float* out1 = out0 + NB * NS * NI;

  char* ws = (char*)d_ws;
  unsigned char* wv8 = (unsigned char*)(ws);                    //  8,192,000 B
  unsigned char* hb8 = (unsigned char*)(ws + 8192000);          //    786,432 B
  float* dpart       = (float*)(ws + 8978432);                  //  6,144,000 B (500 slices)
  float* betas       = (float*)(ws + 8978432);                  //  reuse: dpart dead after k_reduce
  float* dsum        = (float*)(ws + 15122432);                 //     12,288 B
  float* em          = (float*)(ws + 15134720);                 //    589,824 B
  float* alph        = (float*)(ws + 15724544);                 //    589,824 B
  unsigned short* wbt = (unsigned short*)(ws + 16314368);       //    163,840 B
  unsigned short* wht = (unsigned short*)(ws + 16478208);       //     65,536 B
  unsigned short* xb  = (unsigned short*)(ws + 16543744);       //    786,432 B
  float* ebv          = (float*)(ws + 17330176);                //    128,000 B

  k_transpose<<<dim3(500, 4), 256, 0, stream>>>(Wv, wv8, bv, ebv);
  k_t2b<<<dim3(10, 2), 256, 0, stream>>>(Wb, wbt, 640, 128);
  k_t2b<<<dim3(2, 4), 256, 0, stream>>>(Wh, wht, 128, 256);
  k_xb<<<96, 256, 0, stream>>>(emb, wbt, tc, tcn, xb);
  k_h<<<dim3(24, 2), 256, 0, stream>>>(xb, wht, bh, hb8);
  k_denom<<<3000, 256, 0, stream>>>(hb8, wv8, ebv, dpart);
  k_reduce<<<192, 256, 0, stream>>>(dpart, dsum);
  k_emis<<<64, 64, 0, stream>>>(hb8, wv8, ebv, dsum, src, em);
  k_fb<<<64, 192, 0, stream>>>(Atr, pi, em, alph, betas, out1);
  k_gamma<<<dim3(32, 48), 128, 0, stream>>>(alph, betas, out0);
}